// Round 6
// baseline (235.027 us; speedup 1.0000x reference)
//
#include <hip/hip_runtime.h>

// RBF causal attention: out[m] = sum_{j<=m} exp(-0.125*||q_m - k_j||^2) * v_j
// B=2 H=16 S=2048 D=64, fp32 in/out.
// fp16 hi/lo-split QK (3 MFMAs ~ fp32 accuracy), fp16 PV with p scaled 2^14.
// R12 = R8 inner loop, BM 128->256 with 512-thread/8-wave blocks:
// TLP 3->6 waves/SIMD with the SAME 768-block grid and SAME dbuf LDS
// (3 blocks/CU x 51.2KB = 153.6KB <= 160KB), so the L2 tile-stream regime that
// R8 proved out (FETCH ~= compulsory 26MB) is preserved -- each staged tile now
// feeds 8 waves (per-bh tile traffic 272->144 loads, -47%).
// Lessons enforced: R9 (6 blocks/CU thrashed L2 -> HBM-bound), R11 (per-lane V
// reads quadrupled L2 traffic + 4 blocks/CU write-amplified O atomics 38->144MB),
// R10 (acc-split: QK chain latency is NOT the stall; don't add VALU).
// Kept: in-register P transpose via permlane32_swap, dbuf + 1 barrier/iter,
// XCD-matched preconvert writer, s_setprio, fully-masked wave-iter skip (new).

constexpr int S_LEN = 2048;
constexpr int HD    = 64;
constexpr int BM    = 256;   // Q rows per block (8 waves x 32 rows)
constexpr int BN    = 64;    // K/V rows per tile
constexpr float SCALE = 0.125f;
constexpr float LOG2E = 1.44269504088896f;
constexpr float C2    = 2.f * SCALE * LOG2E;   // coeff on qk term
constexpr int TS = 25600;    // ws bytes per (bh,jt) tile: Khi 8K|Klo 8K|Vt 8K|ksq 256|pad

typedef _Float16 half8  __attribute__((ext_vector_type(8)));
typedef _Float16 half4  __attribute__((ext_vector_type(4)));
typedef _Float16 half2v __attribute__((ext_vector_type(2)));
typedef float    f32x4  __attribute__((ext_vector_type(4)));
typedef float    f32x16 __attribute__((ext_vector_type(16)));
typedef unsigned int uint4v __attribute__((ext_vector_type(4)));
typedef unsigned int uint2v __attribute__((ext_vector_type(2)));

// 16B-chunk XOR swizzle (rows of 64 halves = 8 chunks of 8 halves).
__device__ __forceinline__ int swz(int row, int chunk) {
  return (row << 3) + (chunk ^ (row & 7));
}

// ---------------- pass 1: preconvert K/V into LDS-image tiles in ws ----------
// Writer block x runs on XCD x&7 (round-robin dispatch); map so tile (bh,jt)
// is written from XCD bh>>2 -- the consumer's L2 slice.
__global__ __launch_bounds__(256, 4)
void preconvert(const float* __restrict__ Kp, const float* __restrict__ Vp,
                char* __restrict__ ws) {
  const int x  = blockIdx.x;
  const int bh = (x & 7) * 4 + ((x >> 3) & 3);
  const int jt = x >> 5;
  const int t  = threadIdx.x;
  const int w  = t >> 6, lane = t & 63;

  char* img = ws + (size_t)(bh * 32 + jt) * TS;
  half8* imgKh = (half8*)img;
  half8* imgKl = imgKh + 512;
  half8* imgVt = imgKh + 1024;
  float* ksqp  = (float*)(img + 24576);

  const float* Kt = Kp + ((size_t)bh * S_LEN + jt * BN) * HD;
  const float* Vt = Vp + ((size_t)bh * S_LEN + jt * BN) * HD;

  #pragma unroll
  for (int i = 0; i < 4; ++i) {
    const int id  = t + 256 * i;
    const int row = id >> 4;
    const int d4  = id & 15;
    const f32x4 f = *(const f32x4*)(Kt + row * HD + d4 * 4);
    half4 hv, lv;
    float ss = 0.f;
    #pragma unroll
    for (int c = 0; c < 4; ++c) {
      const float fv = f[c];
      const _Float16 hi = (_Float16)fv;
      hv[c] = hi;
      lv[c] = (_Float16)(fv - (float)hi);
      ss += fv * fv;
    }
    ((half4*)&imgKh[swz(row, d4 >> 1)])[d4 & 1] = hv;
    ((half4*)&imgKl[swz(row, d4 >> 1)])[d4 & 1] = lv;
    #pragma unroll
    for (int m = 1; m < 16; m <<= 1) ss += __shfl_xor(ss, m);
    if ((t & 15) == 0) ksqp[row] = ss * (SCALE * LOG2E) - 14.0f;  // bias folded
  }
  // V transpose: lane holds col d=lane, rows w*16..w*16+15
  float vr[16];
  #pragma unroll
  for (int i = 0; i < 16; ++i) vr[i] = Vt[(w * 16 + i) * HD + lane];
  half8 v0, v1;
  #pragma unroll
  for (int i = 0; i < 8; ++i) { v0[i] = (_Float16)vr[i]; v1[i] = (_Float16)vr[8 + i]; }
  imgVt[swz(lane, 2 * w + 0)] = v0;
  imgVt[swz(lane, 2 * w + 1)] = v1;
}

// ---------------- main kernel ------------------------------------------------
__global__ __launch_bounds__(512, 6)
void rbf_causal_attn(const float* __restrict__ Qp, const char* __restrict__ ws,
                     float* __restrict__ Op) {
  __shared__ __align__(16) char sTile[2][TS];  // double-buffered Khi|Klo|Vt|ksq image

  const int x    = blockIdx.x;                 // 0..767
  const int xcd  = x & 7;
  const int idx  = x >> 3;                     // 0..95
  const int bh   = xcd * 4 + (idx & 3);        // 4 bh per XCD (L2 reuse of ws)
  const int a    = idx >> 2;                   // arc 0..23
  const int t    = threadIdx.x;
  const int w    = t >> 6;                     // 0..7
  const int lane = t & 63;
  const int l31  = lane & 31;
  const int l5   = lane >> 5;                  // 0/1

  // 144 j-iters per bh (qt=7..0, each with 4qt+4 j-tiles); 24 arcs x 6 iters
  const int start = 6 * a;
  const int len   = 6;

  // flattened (qt descending, jt ascending) -> (qt, jt)
  int rem = start, qt = 7;
  while (rem >= 4 * qt + 4) { rem -= 4 * qt + 4; --qt; }
  int jt = rem;

  const char* wsb = ws + (size_t)bh * 32 * TS;

  half8 qh[4], ql[4];   // B-operand Q frags: lane holds row w*32+l31, k-chunk ks*16+l5*8
  float qsq;            // SCALE*LOG2E*|q_row|^2
  f32x16 oacc[2];       // O accumulator (x 2^14), dtile 0/1
  #pragma unroll
  for (int d = 0; d < 2; ++d)
    #pragma unroll
    for (int e = 0; e < 16; ++e) oacc[d][e] = 0.f;

  auto load_q = [&](int qtile) {
    const float* Qg = Qp + ((size_t)bh * S_LEN + (size_t)qtile * BM + w * 32 + l31) * HD;
    float ss = 0.f;
    #pragma unroll
    for (int ks = 0; ks < 4; ++ks) {
      const int d0 = ks * 16 + l5 * 8;
      const f32x4 fa = *(const f32x4*)(Qg + d0);
      const f32x4 fb = *(const f32x4*)(Qg + d0 + 4);
      half8 h, l;
      #pragma unroll
      for (int c = 0; c < 4; ++c) {
        const float va = fa[c], vb = fb[c];
        const _Float16 ha = (_Float16)va, hb = (_Float16)vb;
        h[c] = ha;  h[c + 4] = hb;
        l[c] = (_Float16)(va - (float)ha);
        l[c + 4] = (_Float16)(vb - (float)hb);
        ss += va * va + vb * vb;
      }
      qh[ks] = h;  ql[ks] = l;
    }
    ss += __shfl_xor(ss, 32);   // combine l5 halves -> full row sum
    qsq = ss * (SCALE * LOG2E);
  };

  auto flush = [&](int qtile) {
    #pragma unroll
    for (int dt = 0; dt < 2; ++dt)
      #pragma unroll
      for (int r = 0; r < 16; ++r) {
        const int row = qtile * BM + w * 32 + (r & 3) + 8 * (r >> 2) + 4 * l5;
        atomicAdd(Op + ((size_t)bh * S_LEN + row) * HD + dt * 32 + l31,
                  oacc[dt][r] * 6.103515625e-05f);   // * 2^-14
      }
  };

  auto zacc = [&]() {
    #pragma unroll
    for (int d = 0; d < 2; ++d)
      #pragma unroll
      for (int e = 0; e < 16; ++e) oacc[d][e] = 0.f;
  };

  // issue global->LDS DMA of tile jtile into buffer p (no wait here).
  // 8 waves x 3 chunks x 1KB = 24KB (Khi|Klo|Vt); w0 adds ksq+pad (1KB).
  auto stage = [&](int p, int jtile) {
    const char* gt = wsb + (size_t)jtile * TS;
    char* dst = sTile[p];
    #pragma unroll
    for (int i = 0; i < 3; ++i) {
      const int off = w * 3072 + i * 1024;
      __builtin_amdgcn_global_load_lds((const unsigned int*)(gt + off + lane * 16),
                                       (unsigned int*)(dst + off), 16, 0, 0);
    }
    if (w == 0)
      __builtin_amdgcn_global_load_lds((const unsigned int*)(gt + 24576 + lane * 16),
                                       (unsigned int*)(dst + 24576), 16, 0, 0);
  };

  // pack two fp32 -> one u32 of 2 x fp16 (RNE, same numerics as before)
  auto pk = [&](float xx, float yy) -> unsigned int {
    half2v h;
    h[0] = (_Float16)xx;
    h[1] = (_Float16)yy;
    return __builtin_bit_cast(unsigned int, h);
  };

  load_q(qt);
  stage(0, jt);
  __syncthreads();             // prologue drain: buffer 0 ready

  bool newq = false;
  #pragma unroll 1
  for (int step = 0; step < len; ++step) {
    const int p = step & 1;

    // next-step tile indices (uniform across block)
    int jn = jt + 1, qn = qt;
    const bool cross = (jn > 4 * qt + 3);
    if (cross) { jn = 0; qn = qt - 1; }

    // issue next tile's DMA into the idle buffer ASAP (hidden under compute)
    if (step + 1 < len) stage(p ^ 1, jn);

    // q-tile boundary bookkeeping (rare; overlaps the in-flight stage)
    if (newq) { flush(qt + 1); zacc(); load_q(qt); newq = false; }

    const half8* bKh  = (const half8*)sTile[p];
    const half8* bKl  = bKh + 512;
    const half8* bVt  = bKh + 1024;
    const float* bksq = (const float*)(sTile[p] + 24576);

    const int mg = qt * BM + w * 32 + l31;       // this lane's q row
    const int mgmax = qt * BM + w * 32 + 31;     // wave's max q row

    // fully-masked wave-iter (this wave's rows all above the k-tile): skip.
    if (jt * BN <= mgmax) {
      #pragma unroll
      for (int ntile = 0; ntile < 2; ++ntile) {
        // per-ntile full-mask skip (upper half-tile on the diagonal)
        if (jt * BN + ntile * 32 > mgmax) continue;
        const bool need_mask = (jt * BN + ntile * 32 + 31 > qt * BM + w * 32);

        // ---- S^T = K * Q^T (hi/lo) ----
        f32x16 acc;
        #pragma unroll
        for (int e = 0; e < 16; ++e) acc[e] = 0.f;
        __builtin_amdgcn_s_setprio(1);
        #pragma unroll
        for (int ks = 0; ks < 4; ++ks) {
          const int rr = ntile * 32 + l31;
          const int ch = (2 * ks + l5) ^ (rr & 7);
          const half8 kh = bKh[(rr << 3) + ch];
          const half8 kl = bKl[(rr << 3) + ch];
          acc = __builtin_amdgcn_mfma_f32_32x32x16_f16(kh, qh[ks], acc, 0, 0, 0);
          acc = __builtin_amdgcn_mfma_f32_32x32x16_f16(kh, ql[ks], acc, 0, 0, 0);
          acc = __builtin_amdgcn_mfma_f32_32x32x16_f16(kl, qh[ks], acc, 0, 0, 0);
        }
        __builtin_amdgcn_s_setprio(0);

        // ---- p = exp2(C2*qk - qsq' - ksq') in-place in acc ----
        #pragma unroll
        for (int g = 0; g < 4; ++g) {
          const f32x4 k4 = *(const f32x4*)(bksq + ntile * 32 + 8 * g + 4 * l5);
          #pragma unroll
          for (int rr2 = 0; rr2 < 4; ++rr2) {
            const int reg = g * 4 + rr2;
            const float lg = __builtin_fmaf(C2, acc[reg], -k4[rr2]) - qsq;
            float pv = __builtin_amdgcn_exp2f(lg);
            if (need_mask) {
              const int ng = jt * BN + ntile * 32 + 8 * g + 4 * l5 + rr2;
              if (ng > mg) pv = 0.f;
            }
            acc[reg] = pv;
          }
        }

        // ---- in-register C->A transpose: pack + permlane32_swap, then PV ----
        // acc[r] = P[k_loc=(r&3)+8*(r>>2)+4*l5][q=l31]. PV A-frag for lane
        // (l31,l5) needs P[q=l31][k=16*ks2+8*l5+e], e=0..7:
        //   lanes<32 : [own regs 8ks2..+3            | (lane+32)'s regs 8ks2..+3 ]
        //   lanes>=32: [(lane-32)'s regs 8ks2+4..+7  | own regs 8ks2+4..+7       ]
        // v_permlane32_swap_b32 vdst,vsrc swaps VDST.lanes[32:63]<->VSRC.lanes[0:31]:
        //   newA = [ownA | partnerLow_B], newB = [partnerHigh_A | ownB]
        // -> pa = {newA0,newA1,newB0,newB1}.
        #pragma unroll
        for (int ks2 = 0; ks2 < 2; ++ks2) {
          const unsigned int a0 = pk(acc[8 * ks2 + 0], acc[8 * ks2 + 1]);
          const unsigned int a1 = pk(acc[8 * ks2 + 2], acc[8 * ks2 + 3]);
          const unsigned int b0 = pk(acc[8 * ks2 + 4], acc[8 * ks2 + 5]);
          const unsigned int b1 = pk(acc[8 * ks2 + 6], acc[8 * ks2 + 7]);
          const uint2v r0 = __builtin_amdgcn_permlane32_swap(a0, b0, false, false);
          const uint2v r1 = __builtin_amdgcn_permlane32_swap(a1, b1, false, false);
          uint4v wv;
          wv[0] = r0[0];  wv[1] = r1[0];   // own/partner A side (elements 0..3)
          wv[2] = r0[1];  wv[3] = r1[1];   // own/partner B side (elements 4..7)
          const half8 pa = __builtin_bit_cast(half8, wv);

          const int ks = ntile * 2 + ks2;
          __builtin_amdgcn_s_setprio(1);
          #pragma unroll
          for (int dt = 0; dt < 2; ++dt) {
            const int rr = dt * 32 + l31;
            const half8 vt = bVt[(rr << 3) + ((2 * ks + l5) ^ (rr & 7))];
            oacc[dt] = __builtin_amdgcn_mfma_f32_32x32x16_f16(pa, vt, oacc[dt], 0, 0, 0);
          }
          __builtin_amdgcn_s_setprio(0);
        }
      }
    }

    // single barrier per iter: drains this iter's stage DMA (latency already
    // hidden under QK/exp/PV) and protects both LDS buffers.
    __syncthreads();

    jt = jn;
    if (cross) { qt = qn; newq = true; }
  }
  flush(newq ? qt + 1 : qt);
}

extern "C" void kernel_launch(void* const* d_in, const int* in_sizes, int n_in,
                              void* d_out, int out_size, void* d_ws, size_t ws_size,
                              hipStream_t stream) {
  const float* q = (const float*)d_in[0];
  const float* k = (const float*)d_in[1];
  const float* v = (const float*)d_in[2];
  float* o = (float*)d_out;
  hipMemsetAsync(d_out, 0, (size_t)out_size * sizeof(float), stream);
  preconvert<<<dim3(1024), dim3(256), 0, stream>>>(k, v, (char*)d_ws);
  rbf_causal_attn<<<dim3(768), dim3(512), 0, stream>>>(q, (const char*)d_ws, o);
}

// Round 7
// 154.211 us; speedup vs baseline: 1.5241x; 1.5241x over previous
//
#include <hip/hip_runtime.h>

// RBF causal attention: out[m] = sum_{j<=m} exp(-0.125*||q_m - k_j||^2) * v_j
// B=2 H=16 S=2048 D=64, fp32 in/out.
// fp16 hi/lo-split QK (3 MFMAs ~ fp32 accuracy), fp16 PV with p scaled 2^14.
// R13 = R8 (66.5us base) with ONLY the sync structure changed (T3/T4 counted
// vmcnt): R8's __syncthreads = "s_waitcnt vmcnt(0) lgkmcnt(0); s_barrier"
// drained the stage DMA issued at the top of the SAME iteration -> the 25.6KB
// L2->LDS transfer had only the ~1k-cy compute phase to land, and its multi-k-cy
// round-trip was eaten at the barrier every iter (per-SIMD busy only ~13%).
// Now: stage(p^1) -> s_waitcnt vmcnt(7) (waits only the OLDER 7 loads = buffer
// p's; the 7 just issued stay in flight) -> raw s_barrier -> compute(p) -> raw
// s_barrier. Stage loads span a full iteration + both barriers.
// Uniform count: every wave issues exactly 7 loads/stage (6 chunks + lane<16
// slice of the ksq KB). newq path + last iter drain vmcnt(0) (counts stay exact:
// flush atomics & load_q loads never alias the counted stage queue).
// Race ledger: p-ready = vmcnt(7)+barrierA; read-release = barrierB before next
// stage overwrite; ds_reads consumed (lgkm) before barB via MFMA data deps.
// Lessons enforced: R9/R11/R12 = any grid/block reshape breaks the L2 regime
// (768x256thr, 3 blk/CU, dbuf is the proven config); R10 = don't add VALU.

constexpr int S_LEN = 2048;
constexpr int HD    = 64;
constexpr int BM    = 128;   // Q rows per block (4 waves x 32 rows)
constexpr int BN    = 64;    // K/V rows per tile
constexpr float SCALE = 0.125f;
constexpr float LOG2E = 1.44269504088896f;
constexpr float C2    = 2.f * SCALE * LOG2E;   // coeff on qk term
constexpr int TS = 25600;    // ws bytes per (bh,jt) tile: Khi 8K|Klo 8K|Vt 8K|ksq 256|pad

typedef _Float16 half8  __attribute__((ext_vector_type(8)));
typedef _Float16 half4  __attribute__((ext_vector_type(4)));
typedef _Float16 half2v __attribute__((ext_vector_type(2)));
typedef float    f32x4  __attribute__((ext_vector_type(4)));
typedef float    f32x16 __attribute__((ext_vector_type(16)));
typedef unsigned int uint4v __attribute__((ext_vector_type(4)));
typedef unsigned int uint2v __attribute__((ext_vector_type(2)));

// 16B-chunk XOR swizzle (rows of 64 halves = 8 chunks of 8 halves).
__device__ __forceinline__ int swz(int row, int chunk) {
  return (row << 3) + (chunk ^ (row & 7));
}

// ---------------- pass 1: preconvert K/V into LDS-image tiles in ws ----------
// Writer block x runs on XCD x&7 (round-robin dispatch); map so tile (bh,jt)
// is written from XCD bh>>2 -- the consumer's L2 slice.
__global__ __launch_bounds__(256, 4)
void preconvert(const float* __restrict__ Kp, const float* __restrict__ Vp,
                char* __restrict__ ws) {
  const int x  = blockIdx.x;
  const int bh = (x & 7) * 4 + ((x >> 3) & 3);
  const int jt = x >> 5;
  const int t  = threadIdx.x;
  const int w  = t >> 6, lane = t & 63;

  char* img = ws + (size_t)(bh * 32 + jt) * TS;
  half8* imgKh = (half8*)img;
  half8* imgKl = imgKh + 512;
  half8* imgVt = imgKh + 1024;
  float* ksqp  = (float*)(img + 24576);

  const float* Kt = Kp + ((size_t)bh * S_LEN + jt * BN) * HD;
  const float* Vt = Vp + ((size_t)bh * S_LEN + jt * BN) * HD;

  #pragma unroll
  for (int i = 0; i < 4; ++i) {
    const int id  = t + 256 * i;
    const int row = id >> 4;
    const int d4  = id & 15;
    const f32x4 f = *(const f32x4*)(Kt + row * HD + d4 * 4);
    half4 hv, lv;
    float ss = 0.f;
    #pragma unroll
    for (int c = 0; c < 4; ++c) {
      const float fv = f[c];
      const _Float16 hi = (_Float16)fv;
      hv[c] = hi;
      lv[c] = (_Float16)(fv - (float)hi);
      ss += fv * fv;
    }
    ((half4*)&imgKh[swz(row, d4 >> 1)])[d4 & 1] = hv;
    ((half4*)&imgKl[swz(row, d4 >> 1)])[d4 & 1] = lv;
    #pragma unroll
    for (int m = 1; m < 16; m <<= 1) ss += __shfl_xor(ss, m);
    if ((t & 15) == 0) ksqp[row] = ss * (SCALE * LOG2E) - 14.0f;  // bias folded
  }
  // V transpose: lane holds col d=lane, rows w*16..w*16+15
  float vr[16];
  #pragma unroll
  for (int i = 0; i < 16; ++i) vr[i] = Vt[(w * 16 + i) * HD + lane];
  half8 v0, v1;
  #pragma unroll
  for (int i = 0; i < 8; ++i) { v0[i] = (_Float16)vr[i]; v1[i] = (_Float16)vr[8 + i]; }
  imgVt[swz(lane, 2 * w + 0)] = v0;
  imgVt[swz(lane, 2 * w + 1)] = v1;
}

// ---------------- main kernel ------------------------------------------------
__global__ __launch_bounds__(256, 3)
void rbf_causal_attn(const float* __restrict__ Qp, const char* __restrict__ ws,
                     float* __restrict__ Op) {
  __shared__ __align__(16) char sTile[2][TS];  // double-buffered Khi|Klo|Vt|ksq image

  const int x    = blockIdx.x;                 // 0..767
  const int xcd  = x & 7;
  const int idx  = x >> 3;                     // 0..95
  const int bh   = xcd * 4 + (idx & 3);        // 4 bh per XCD (L2 reuse of ws)
  const int a    = idx >> 2;                   // arc 0..23
  const int t    = threadIdx.x;
  const int w    = t >> 6;
  const int lane = t & 63;
  const int l31  = lane & 31;
  const int l5   = lane >> 5;                  // 0/1

  // arc: first 8 arcs take 12 j-iters, rest 11 (total 272 per bh)
  const int start = (a < 8) ? 12 * a : 96 + 11 * (a - 8);
  const int len   = (a < 8) ? 12 : 11;

  // flattened (qt descending, jt ascending) -> (qt, jt)
  int rem = start, qt = 15;
  while (rem >= 2 * qt + 2) { rem -= 2 * qt + 2; --qt; }
  int jt = rem;

  const char* wsb = ws + (size_t)bh * 32 * TS;

  half8 qh[4], ql[4];   // B-operand Q frags: lane holds row w*32+l31, k-chunk ks*16+l5*8
  float qsq;            // SCALE*LOG2E*|q_row|^2
  f32x16 oacc[2];       // O accumulator (x 2^14), dtile 0/1
  #pragma unroll
  for (int d = 0; d < 2; ++d)
    #pragma unroll
    for (int e = 0; e < 16; ++e) oacc[d][e] = 0.f;

  auto load_q = [&](int qtile) {
    const float* Qg = Qp + ((size_t)bh * S_LEN + (size_t)qtile * BM + w * 32 + l31) * HD;
    float ss = 0.f;
    #pragma unroll
    for (int ks = 0; ks < 4; ++ks) {
      const int d0 = ks * 16 + l5 * 8;
      const f32x4 fa = *(const f32x4*)(Qg + d0);
      const f32x4 fb = *(const f32x4*)(Qg + d0 + 4);
      half8 h, l;
      #pragma unroll
      for (int c = 0; c < 4; ++c) {
        const float va = fa[c], vb = fb[c];
        const _Float16 ha = (_Float16)va, hb = (_Float16)vb;
        h[c] = ha;  h[c + 4] = hb;
        l[c] = (_Float16)(va - (float)ha);
        l[c + 4] = (_Float16)(vb - (float)hb);
        ss += va * va + vb * vb;
      }
      qh[ks] = h;  ql[ks] = l;
    }
    ss += __shfl_xor(ss, 32);   // combine l5 halves -> full row sum
    qsq = ss * (SCALE * LOG2E);
  };

  auto flush = [&](int qtile) {
    #pragma unroll
    for (int dt = 0; dt < 2; ++dt)
      #pragma unroll
      for (int r = 0; r < 16; ++r) {
        const int row = qtile * BM + w * 32 + (r & 3) + 8 * (r >> 2) + 4 * l5;
        atomicAdd(Op + ((size_t)bh * S_LEN + row) * HD + dt * 32 + l31,
                  oacc[dt][r] * 6.103515625e-05f);   // * 2^-14
      }
  };

  auto zacc = [&]() {
    #pragma unroll
    for (int d = 0; d < 2; ++d)
      #pragma unroll
      for (int e = 0; e < 16; ++e) oacc[d][e] = 0.f;
  };

  // issue global->LDS DMA of tile jtile into buffer p. EXACTLY 7 VMEM ops per
  // wave (uniform vmcnt accounting): 6x 1KB chunks + 1x 256B ksq/pad slice
  // (lanes 0..15; wave w covers bytes 24576+w*256..+255 -- w0's is real ksq).
  auto stage = [&](int p, int jtile) {
    const char* gt = wsb + (size_t)jtile * TS;
    char* dst = sTile[p];
    #pragma unroll
    for (int i = 0; i < 6; ++i) {
      const int off = w * 6144 + i * 1024;
      __builtin_amdgcn_global_load_lds((const unsigned int*)(gt + off + lane * 16),
                                       (unsigned int*)(dst + off), 16, 0, 0);
    }
    const int koff = 24576 + w * 256 + (lane & 15) * 16;
    if (lane < 16)
      __builtin_amdgcn_global_load_lds((const unsigned int*)(gt + koff),
                                       (unsigned int*)(dst + koff), 16, 0, 0);
  };

  // pack two fp32 -> one u32 of 2 x fp16 (RNE, same numerics as before)
  auto pk = [&](float xx, float yy) -> unsigned int {
    half2v h;
    h[0] = (_Float16)xx;
    h[1] = (_Float16)yy;
    return __builtin_bit_cast(unsigned int, h);
  };

  load_q(qt);
  stage(0, jt);                // 7 loads in flight (buffer 0)

  bool newq = false;
  #pragma unroll 1
  for (int step = 0; step < len; ++step) {
    const int p = step & 1;

    // next-step tile indices (uniform across block)
    int jn = jt + 1, qn = qt;
    const bool cross = (jn > 2 * qt + 1);
    if (cross) { jn = 0; qn = qt - 1; }

    // rare q-tile bookkeeping BEFORE issuing the next stage: its atomics/loads
    // would corrupt the vmcnt ledger, so drain to a clean state afterwards
    // (this also completes buffer p's loads; ~1-2 times per block life).
    if (newq) {
      flush(qt + 1); zacc(); load_q(qt);
      asm volatile("s_waitcnt vmcnt(0)" ::: "memory");
      newq = false;
    }

    if (step + 1 < len) {
      stage(p ^ 1, jn);        // +7 loads (buffer p^1), stay in flight all iter
      asm volatile("s_waitcnt vmcnt(7)" ::: "memory");  // older 7 (= p) done
    } else {
      asm volatile("s_waitcnt vmcnt(0)" ::: "memory");  // last iter: p done
    }
    __builtin_amdgcn_s_barrier();   // A: every wave's p-loads complete

    const half8* bKh  = (const half8*)sTile[p];
    const half8* bKl  = bKh + 512;
    const half8* bVt  = bKh + 1024;
    const float* bksq = (const float*)(sTile[p] + 24576);

    const bool need_mask = (jt >= 2 * qt);
    const int mg = qt * BM + w * 32 + l31;

    #pragma unroll
    for (int ntile = 0; ntile < 2; ++ntile) {
      // ---- S^T = K * Q^T (hi/lo) ----
      f32x16 acc;
      #pragma unroll
      for (int e = 0; e < 16; ++e) acc[e] = 0.f;
      __builtin_amdgcn_s_setprio(1);
      #pragma unroll
      for (int ks = 0; ks < 4; ++ks) {
        const int rr = ntile * 32 + l31;
        const int ch = (2 * ks + l5) ^ (rr & 7);
        const half8 kh = bKh[(rr << 3) + ch];
        const half8 kl = bKl[(rr << 3) + ch];
        acc = __builtin_amdgcn_mfma_f32_32x32x16_f16(kh, qh[ks], acc, 0, 0, 0);
        acc = __builtin_amdgcn_mfma_f32_32x32x16_f16(kh, ql[ks], acc, 0, 0, 0);
        acc = __builtin_amdgcn_mfma_f32_32x32x16_f16(kl, qh[ks], acc, 0, 0, 0);
      }
      __builtin_amdgcn_s_setprio(0);

      // ---- p = exp2(C2*qk - qsq' - ksq') in-place in acc ----
      #pragma unroll
      for (int g = 0; g < 4; ++g) {
        const f32x4 k4 = *(const f32x4*)(bksq + ntile * 32 + 8 * g + 4 * l5);
        #pragma unroll
        for (int rr2 = 0; rr2 < 4; ++rr2) {
          const int reg = g * 4 + rr2;
          const float lg = __builtin_fmaf(C2, acc[reg], -k4[rr2]) - qsq;
          float pv = __builtin_amdgcn_exp2f(lg);
          if (need_mask) {
            const int ng = jt * BN + ntile * 32 + 8 * g + 4 * l5 + rr2;
            if (ng > mg) pv = 0.f;
          }
          acc[reg] = pv;
        }
      }

      // ---- in-register C->A transpose: pack + permlane32_swap, then PV ----
      // acc[r] = P[k_loc=(r&3)+8*(r>>2)+4*l5][q=l31]. PV A-frag for lane
      // (l31,l5) needs P[q=l31][k=16*ks2+8*l5+e], e=0..7:
      //   lanes<32 : [own regs 8ks2..+3            | (lane+32)'s regs 8ks2..+3 ]
      //   lanes>=32: [(lane-32)'s regs 8ks2+4..+7  | own regs 8ks2+4..+7       ]
      // v_permlane32_swap_b32 vdst,vsrc swaps VDST.lanes[32:63]<->VSRC.lanes[0:31]:
      //   newA = [ownA | partnerLow_B], newB = [partnerHigh_A | ownB]
      // -> pa = {newA0,newA1,newB0,newB1}.
      #pragma unroll
      for (int ks2 = 0; ks2 < 2; ++ks2) {
        const unsigned int a0 = pk(acc[8 * ks2 + 0], acc[8 * ks2 + 1]);
        const unsigned int a1 = pk(acc[8 * ks2 + 2], acc[8 * ks2 + 3]);
        const unsigned int b0 = pk(acc[8 * ks2 + 4], acc[8 * ks2 + 5]);
        const unsigned int b1 = pk(acc[8 * ks2 + 6], acc[8 * ks2 + 7]);
        const uint2v r0 = __builtin_amdgcn_permlane32_swap(a0, b0, false, false);
        const uint2v r1 = __builtin_amdgcn_permlane32_swap(a1, b1, false, false);
        uint4v wv;
        wv[0] = r0[0];  wv[1] = r1[0];   // own/partner A side (elements 0..3)
        wv[2] = r0[1];  wv[3] = r1[1];   // own/partner B side (elements 4..7)
        const half8 pa = __builtin_bit_cast(half8, wv);

        const int ks = ntile * 2 + ks2;
        __builtin_amdgcn_s_setprio(1);
        #pragma unroll
        for (int dt = 0; dt < 2; ++dt) {
          const int rr = dt * 32 + l31;
          const half8 vt = bVt[(rr << 3) + ((2 * ks + l5) ^ (rr & 7))];
          oacc[dt] = __builtin_amdgcn_mfma_f32_32x32x16_f16(pa, vt, oacc[dt], 0, 0, 0);
        }
        __builtin_amdgcn_s_setprio(0);
      }
    }

    // B: all waves done reading buffer p (ds_read results consumed via MFMA
    // data deps) -> next iteration's stage(p) may overwrite it. Raw barrier:
    // the in-flight p^1 loads are NOT drained here (that's the whole point).
    __builtin_amdgcn_s_barrier();

    jt = jn;
    if (cross) { qt = qn; newq = true; }
  }
  flush(newq ? qt + 1 : qt);
}

extern "C" void kernel_launch(void* const* d_in, const int* in_sizes, int n_in,
                              void* d_out, int out_size, void* d_ws, size_t ws_size,
                              hipStream_t stream) {
  const float* q = (const float*)d_in[0];
  const float* k = (const float*)d_in[1];
  const float* v = (const float*)d_in[2];
  float* o = (float*)d_out;
  hipMemsetAsync(d_out, 0, (size_t)out_size * sizeof(float), stream);
  preconvert<<<dim3(1024), dim3(256), 0, stream>>>(k, v, (char*)d_ws);
  rbf_causal_attn<<<dim3(768), dim3(256), 0, stream>>>(q, (const char*)d_ws, o);
}

// Round 9
// 150.523 us; speedup vs baseline: 1.5614x; 1.0245x over previous
//
#include <hip/hip_runtime.h>

// RBF causal attention: out[m] = sum_{j<=m} exp(-0.125*||q_m - k_j||^2) * v_j
// B=2 H=16 S=2048 D=64, fp32 in/out.
// fp16 hi/lo-split QK (3 MFMAs ~ fp32 accuracy), fp16 PV with p scaled 2^14.
// R15 = R14 with the tile-image offset bug fixed (R14's +2048/+4096 half8 =
// +32KB/+64KB put Klo in the Vt slot and Vt PAST the 49.7KB tile -> main
// kernel read bVt out of LDS bounds -> garbage V, absmax 2e-2).
// Correct layout (half8 units): Khi[0,1024) | Klo[1024,2048) | Vt[2048,3072)
// = bytes [0,16K)|[16K,32K)|[32K,48K), ksq at byte 49152. TS2=49664.
// R14's actual experiment (now live): per-SIMD model shows R8/R13 jointly
// pipe-loaded but PHASE-SERIALIZED (MFMA 3.1k cy + VALU 4.2k cy per 13.7k-cy
// iter, alternating QK->exp->PV). Fix without new parallelism (R9/R11/R12:
// more blocks/waves breaks the L2 regime):
// (a) BN 64->128: 136 iters/bh, 4 ntiles/iter, single-buffered 49.7KB tile,
//     SAME 768x256t grid / 3 blocks/CU / 4 bh/XCD.
// (b) clean-tile body software-pipelined IN-WAVE: QK(n+1) and {exp+pack(n),
//     PV(n)} in one branch-free block -> MFMA interleaves with VALU.
// (c) diagonal tiles (jt==qt, 16/136): ntile>w skipped, ntile==w masked.
// (d) plain 2x __syncthreads (R13: counted vmcnt null).

constexpr int S_LEN = 2048;
constexpr int HD    = 64;
constexpr int BM    = 128;   // Q rows per block (4 waves x 32 rows)
constexpr int BN    = 128;   // K/V rows per tile (4 ntiles of 32)
constexpr float SCALE = 0.125f;
constexpr float LOG2E = 1.44269504088896f;
constexpr float C2    = 2.f * SCALE * LOG2E;   // coeff on qk term
constexpr int TS2 = 49664;   // ws bytes/tile: Khi 16K|Klo 16K|Vt 16K|ksq 512

typedef _Float16 half8  __attribute__((ext_vector_type(8)));
typedef _Float16 half4  __attribute__((ext_vector_type(4)));
typedef _Float16 half2v __attribute__((ext_vector_type(2)));
typedef float    f32x4  __attribute__((ext_vector_type(4)));
typedef float    f32x16 __attribute__((ext_vector_type(16)));
typedef unsigned int uint4v __attribute__((ext_vector_type(4)));
typedef unsigned int uint2v __attribute__((ext_vector_type(2)));

// ---------------- pass 1: preconvert K/V into LDS-image tiles in ws ----------
// Writer block x runs on XCD x&7; map so tile (bh,jt) is written from XCD
// bh>>2 -- the consumer's L2 slice. Grid: 32 bh x 16 jt = 512 blocks.
__global__ __launch_bounds__(256, 4)
void preconvert(const float* __restrict__ Kp, const float* __restrict__ Vp,
                char* __restrict__ ws) {
  const int x  = blockIdx.x;
  const int bh = (x & 7) * 4 + ((x >> 3) & 3);
  const int jt = x >> 5;                        // 0..15
  const int t  = threadIdx.x;
  const int w  = t >> 6, lane = t & 63;

  char* img = ws + (size_t)(bh * 16 + jt) * TS2;
  half8* imgKh = (half8*)img;           // [128 rows][8 chunks] swizzled, 1024 half8
  half8* imgKl = imgKh + 1024;          // +16KB
  half8* imgVt = imgKh + 2048;          // +32KB: [64 rows(d)][16 chunks] swizzled
  float* ksqp  = (float*)(img + 49152); // 128 floats

  const float* Kt = Kp + ((size_t)bh * S_LEN + jt * BN) * HD;
  const float* Vt = Vp + ((size_t)bh * S_LEN + jt * BN) * HD;

  #pragma unroll
  for (int i = 0; i < 8; ++i) {
    const int id  = t + 256 * i;
    const int row = id >> 4;            // 0..127
    const int d4  = id & 15;
    const f32x4 f = *(const f32x4*)(Kt + row * HD + d4 * 4);
    half4 hv, lv;
    float ss = 0.f;
    #pragma unroll
    for (int c = 0; c < 4; ++c) {
      const float fv = f[c];
      const _Float16 hi = (_Float16)fv;
      hv[c] = hi;
      lv[c] = (_Float16)(fv - (float)hi);
      ss += fv * fv;
    }
    const int idx8 = (row << 3) + ((d4 >> 1) ^ (row & 7));   // <= 1023
    ((half4*)&imgKh[idx8])[d4 & 1] = hv;
    ((half4*)&imgKl[idx8])[d4 & 1] = lv;
    #pragma unroll
    for (int m = 1; m < 16; m <<= 1) ss += __shfl_xor(ss, m);
    if ((t & 15) == 0) ksqp[row] = ss * (SCALE * LOG2E) - 14.0f;  // bias folded
  }
  // V transpose: lane holds col d=lane (row of V^T); wave w covers k-rows
  // w*32..w*32+31 = chunks w*4..w*4+3 of V^T row d.
  float vr[32];
  #pragma unroll
  for (int i = 0; i < 32; ++i) vr[i] = Vt[(w * 32 + i) * HD + lane];
  #pragma unroll
  for (int j = 0; j < 4; ++j) {
    half8 v;
    #pragma unroll
    for (int e = 0; e < 8; ++e) v[e] = (_Float16)vr[j * 8 + e];
    imgVt[(lane << 4) + ((w * 4 + j) ^ (lane & 7))] = v;     // <= 1023
  }
}

// ---------------- main kernel ------------------------------------------------
__global__ __launch_bounds__(256, 3)
void rbf_causal_attn(const float* __restrict__ Qp, const char* __restrict__ ws,
                     float* __restrict__ Op) {
  __shared__ __align__(16) char sTile[TS2];    // Khi|Klo|Vt|ksq image

  const int x    = blockIdx.x;                 // 0..767
  const int xcd  = x & 7;
  const int idx  = x >> 3;                     // 0..95
  const int bh   = xcd * 4 + (idx & 3);        // 4 bh per XCD (L2 reuse of ws)
  const int a    = idx >> 2;                   // arc 0..23
  const int t    = threadIdx.x;
  const int w    = t >> 6;
  const int lane = t & 63;
  const int l31  = lane & 31;
  const int l5   = lane >> 5;                  // 0/1

  // 136 j-iters per bh (qt=15..0, qt+1 tiles each); 16 arcs x 6 + 8 arcs x 5
  const int start = (a < 16) ? 6 * a : 96 + 5 * (a - 16);
  const int len   = (a < 16) ? 6 : 5;

  // flattened (qt descending, jt ascending) -> (qt, jt)
  int rem = start, qt = 15;
  while (rem >= qt + 1) { rem -= qt + 1; --qt; }
  int jt = rem;

  const char* wsb = ws + (size_t)bh * 16 * TS2;

  const half8* bKh  = (const half8*)sTile;     // 1024 half8
  const half8* bKl  = bKh + 1024;              // +16KB
  const half8* bVt  = bKh + 2048;              // +32KB
  const float* bksq = (const float*)(sTile + 49152);

  half8 qh[4], ql[4];   // B-operand Q frags: lane holds row w*32+l31, d-chunk ks*16+l5*8
  float qsq;            // SCALE*LOG2E*|q_row|^2
  f32x16 oacc[2];       // O accumulator (x 2^14), dtile 0/1
  #pragma unroll
  for (int d = 0; d < 2; ++d)
    #pragma unroll
    for (int e = 0; e < 16; ++e) oacc[d][e] = 0.f;

  auto load_q = [&](int qtile) {
    const float* Qg = Qp + ((size_t)bh * S_LEN + (size_t)qtile * BM + w * 32 + l31) * HD;
    float ss = 0.f;
    #pragma unroll
    for (int ks = 0; ks < 4; ++ks) {
      const int d0 = ks * 16 + l5 * 8;
      const f32x4 fa = *(const f32x4*)(Qg + d0);
      const f32x4 fb = *(const f32x4*)(Qg + d0 + 4);
      half8 h, l;
      #pragma unroll
      for (int c = 0; c < 4; ++c) {
        const float va = fa[c], vb = fb[c];
        const _Float16 ha = (_Float16)va, hb = (_Float16)vb;
        h[c] = ha;  h[c + 4] = hb;
        l[c] = (_Float16)(va - (float)ha);
        l[c + 4] = (_Float16)(vb - (float)hb);
        ss += va * va + vb * vb;
      }
      qh[ks] = h;  ql[ks] = l;
    }
    ss += __shfl_xor(ss, 32);   // combine l5 halves -> full row sum
    qsq = ss * (SCALE * LOG2E);
  };

  auto flush = [&](int qtile) {
    #pragma unroll
    for (int dt = 0; dt < 2; ++dt)
      #pragma unroll
      for (int r = 0; r < 16; ++r) {
        const int row = qtile * BM + w * 32 + (r & 3) + 8 * (r >> 2) + 4 * l5;
        atomicAdd(Op + ((size_t)bh * S_LEN + row) * HD + dt * 32 + l31,
                  oacc[dt][r] * 6.103515625e-05f);   // * 2^-14
      }
  };

  auto zacc = [&]() {
    #pragma unroll
    for (int d = 0; d < 2; ++d)
      #pragma unroll
      for (int e = 0; e < 16; ++e) oacc[d][e] = 0.f;
  };

  // issue global->LDS DMA of tile jtile (drained by the following barrier)
  auto stage = [&](int jtile) {
    const char* gt = wsb + (size_t)jtile * TS2;
    #pragma unroll
    for (int i = 0; i < 12; ++i) {            // 48KB K+V
      const int off = w * 12288 + i * 1024;
      __builtin_amdgcn_global_load_lds((const unsigned int*)(gt + off + lane * 16),
                                       (unsigned int*)(sTile + off), 16, 0, 0);
    }
    if (w == 0 && lane < 32)                  // ksq 512B
      __builtin_amdgcn_global_load_lds((const unsigned int*)(gt + 49152 + lane * 16),
                                       (unsigned int*)(sTile + 49152), 16, 0, 0);
  };

  // pack two fp32 -> one u32 of 2 x fp16 (RNE, same numerics as before)
  auto pk = [&](float xx, float yy) -> unsigned int {
    half2v h;
    h[0] = (_Float16)xx;
    h[1] = (_Float16)yy;
    return __builtin_bit_cast(unsigned int, h);
  };

  // ---- building blocks (per 32-row ntile) ----
  auto QK = [&](int ntile, f32x16& acc) {
    #pragma unroll
    for (int e = 0; e < 16; ++e) acc[e] = 0.f;
    const int rr = ntile * 32 + l31;
    #pragma unroll
    for (int ks = 0; ks < 4; ++ks) {
      const int ch = (2 * ks + l5) ^ (rr & 7);
      const half8 kh = bKh[(rr << 3) + ch];
      const half8 kl = bKl[(rr << 3) + ch];
      acc = __builtin_amdgcn_mfma_f32_32x32x16_f16(kh, qh[ks], acc, 0, 0, 0);
      acc = __builtin_amdgcn_mfma_f32_32x32x16_f16(kh, ql[ks], acc, 0, 0, 0);
      acc = __builtin_amdgcn_mfma_f32_32x32x16_f16(kl, qh[ks], acc, 0, 0, 0);
    }
  };

  // exp2 + (optional causal mask, valid only for ntile==w on jt==qt tiles,
  // where mask condition reduces to k_local > l31) + pack into PV A-frags.
  // acc[r] = P[k_loc=(r&3)+8*(r>>2)+4*l5][q=l31]; permlane32_swap(vdst=A,vsrc=B)
  // swaps VDST.hi32lanes <-> VSRC.lo32lanes -> pa = {newA0,newA1,newB0,newB1}
  // = P[q=l31][k=16*ks2+8*l5+0..7].
  auto EXPP = [&](int ntile, f32x16& acc, half8& pa0, half8& pa1, bool domask) {
    #pragma unroll
    for (int g = 0; g < 4; ++g) {
      const f32x4 k4 = *(const f32x4*)(bksq + ntile * 32 + 8 * g + 4 * l5);
      #pragma unroll
      for (int rr2 = 0; rr2 < 4; ++rr2) {
        const int reg = g * 4 + rr2;
        const float lg = __builtin_fmaf(C2, acc[reg], -k4[rr2]) - qsq;
        float pv = __builtin_amdgcn_exp2f(lg);
        if (domask) {
          const int nloc = 8 * g + 4 * l5 + rr2;
          if (nloc > l31) pv = 0.f;
        }
        acc[reg] = pv;
      }
    }
    #pragma unroll
    for (int ks2 = 0; ks2 < 2; ++ks2) {
      const unsigned int a0 = pk(acc[8 * ks2 + 0], acc[8 * ks2 + 1]);
      const unsigned int a1 = pk(acc[8 * ks2 + 2], acc[8 * ks2 + 3]);
      const unsigned int b0 = pk(acc[8 * ks2 + 4], acc[8 * ks2 + 5]);
      const unsigned int b1 = pk(acc[8 * ks2 + 6], acc[8 * ks2 + 7]);
      const uint2v r0 = __builtin_amdgcn_permlane32_swap(a0, b0, false, false);
      const uint2v r1 = __builtin_amdgcn_permlane32_swap(a1, b1, false, false);
      uint4v wv;
      wv[0] = r0[0];  wv[1] = r1[0];
      wv[2] = r0[1];  wv[3] = r1[1];
      if (ks2 == 0) pa0 = __builtin_bit_cast(half8, wv);
      else          pa1 = __builtin_bit_cast(half8, wv);
    }
  };

  auto PVF = [&](int ntile, half8 pa0v, half8 pa1v) {
    #pragma unroll
    for (int ks2 = 0; ks2 < 2; ++ks2) {
      const half8 pa = ks2 ? pa1v : pa0v;
      const int ks = ntile * 2 + ks2;
      #pragma unroll
      for (int dt = 0; dt < 2; ++dt) {
        const int rr = dt * 32 + l31;
        const half8 vt = bVt[(rr << 4) + ((2 * ks + l5) ^ (rr & 7))];
        oacc[dt] = __builtin_amdgcn_mfma_f32_32x32x16_f16(pa, vt, oacc[dt], 0, 0, 0);
      }
    }
  };

  load_q(qt);

  bool newq = false;
  #pragma unroll 1
  for (int step = 0; step < len; ++step) {
    stage(jt);   // previous iteration's end barrier protects sTile

    // q-tile boundary bookkeeping: overlaps the in-flight DMA
    if (newq) { flush(qt + 1); zacc(); load_q(qt); newq = false; }

    __syncthreads();   // drains vmcnt -> tile image ready

    if (jt < qt) {
      // ---- clean tile: software-pipelined 4-ntile body (one basic block) ----
      f32x16 accA, accB;
      half8 pa0, pa1;
      QK(0, accA);
      QK(1, accB);  EXPP(0, accA, pa0, pa1, false);  PVF(0, pa0, pa1);
      QK(2, accA);  EXPP(1, accB, pa0, pa1, false);  PVF(1, pa0, pa1);
      QK(3, accB);  EXPP(2, accA, pa0, pa1, false);  PVF(2, pa0, pa1);
                    EXPP(3, accB, pa0, pa1, false);  PVF(3, pa0, pa1);
    } else {
      // ---- diagonal tile (jt==qt): ntile>w fully masked -> skipped;
      //      ntile==w needs the per-element causal mask ----
      for (int ntile = 0; ntile <= w; ++ntile) {
        f32x16 acc;
        half8 pa0, pa1;
        QK(ntile, acc);
        EXPP(ntile, acc, pa0, pa1, ntile == w);
        PVF(ntile, pa0, pa1);
      }
    }

    __syncthreads();   // all waves done reading sTile before next stage

    ++jt;
    if (jt > qt) { jt = 0; --qt; newq = true; }
  }
  flush(newq ? qt + 1 : qt);
}

extern "C" void kernel_launch(void* const* d_in, const int* in_sizes, int n_in,
                              void* d_out, int out_size, void* d_ws, size_t ws_size,
                              hipStream_t stream) {
  const float* q = (const float*)d_in[0];
  const float* k = (const float*)d_in[1];
  const float* v = (const float*)d_in[2];
  float* o = (float*)d_out;
  hipMemsetAsync(d_out, 0, (size_t)out_size * sizeof(float), stream);
  preconvert<<<dim3(512), dim3(256), 0, stream>>>(k, v, (char*)d_ws);
  rbf_causal_attn<<<dim3(768), dim3(256), 0, stream>>>(q, (const char*)d_ws, o);
}